// Round 14
// baseline (16479.875 us; speedup 1.0000x reference)
//
#include <hip/hip_runtime.h>
#include <math.h>

#define SQ   4096
#define EDIM 512
#define CEDIM 128
#define CHH  128
#define WH   512
#define NT   50

typedef unsigned long long ull;

__device__ __forceinline__ float sigf(float x) { return 1.0f / (1.0f + expf(-x)); }

#define PIN4(V) asm volatile("" : "+v"(V.x), "+v"(V.y), "+v"(V.z), "+v"(V.w));

// ---- tagged-pair helpers (proven recipe) -------------------------------------
__device__ __forceinline__ void ld8x_sc0(const ull* p, ull& q0, ull& q1, ull& q2,
                                         ull& q3, ull& q4, ull& q5, ull& q6, ull& q7) {
    asm volatile("global_load_dwordx2 %0, %8, off sc0\n\t"
                 "global_load_dwordx2 %1, %8, off offset:8 sc0\n\t"
                 "global_load_dwordx2 %2, %8, off offset:16 sc0\n\t"
                 "global_load_dwordx2 %3, %8, off offset:24 sc0\n\t"
                 "global_load_dwordx2 %4, %8, off offset:32 sc0\n\t"
                 "global_load_dwordx2 %5, %8, off offset:40 sc0\n\t"
                 "global_load_dwordx2 %6, %8, off offset:48 sc0\n\t"
                 "global_load_dwordx2 %7, %8, off offset:56 sc0\n\t"
                 "s_waitcnt vmcnt(0)"
                 : "=&v"(q0), "=&v"(q1), "=&v"(q2), "=&v"(q3),
                   "=&v"(q4), "=&v"(q5), "=&v"(q6), "=&v"(q7)
                 : "v"(p) : "memory");
}
__device__ __forceinline__ ull ld_mir(const ull* p) {
    return __hip_atomic_load(p, __ATOMIC_RELAXED, __HIP_MEMORY_SCOPE_AGENT);
}
__device__ __forceinline__ void st_plain8(ull* p, ull v) {
    asm volatile("global_store_dwordx2 %0, %1, off" :: "v"(p), "v"(v) : "memory");
}
__device__ __forceinline__ void st_mir(ull* p, ull v) {
    __hip_atomic_store(p, v, __ATOMIC_RELAXED, __HIP_MEMORY_SCOPE_AGENT);
}
__device__ __forceinline__ unsigned umin2(unsigned a, unsigned b) { return a < b ? a : b; }

#define FMA4(W, off) { float4 h4 = *(const float4*)&hc[off]; \
    a0 += W.x * h4.x; a1 += W.y * h4.y; a2 += W.z * h4.z; a3 += W.w * h4.w; }

// ---------------------------------------------------------------------------
// K1: gather word/char embedding rows; compute char-LSTM input GEMM
// ---------------------------------------------------------------------------
__global__ __launch_bounds__(256) void k1_gather_cgx(
    const int* __restrict__ sent, const int* __restrict__ csent,
    const float* __restrict__ wemb, const float* __restrict__ cemb,
    const float* __restrict__ cWih_f, const float* __restrict__ cb_f,
    const float* __restrict__ cWih_b, const float* __restrict__ cb_b,
    float* __restrict__ we_g, float* __restrict__ cgx)
{
    const int tid = threadIdx.x;
    const int t0 = blockIdx.x * 16;
    __shared__ __align__(16) float ceL[16][128];
    __shared__ int sids[16], cids[16];
    if (tid < 16) sids[tid] = sent[t0 + tid];
    else if (tid < 32) cids[tid - 16] = csent[t0 + tid - 16];
    __syncthreads();
    {
        int f4 = tid;
        for (int q = 0; q < 2; ++q, f4 += 256) {
            int r = f4 >> 5, k4 = f4 & 31;
            float4 v = *(const float4*)&cemb[(size_t)cids[r] * CEDIM + k4 * 4];
            *(float4*)&ceL[r][k4 * 4] = v;
        }
    }
    {
        int f4 = tid;
        for (int q = 0; q < 8; ++q, f4 += 256) {
            int r = f4 >> 7, k4 = f4 & 127;
            float4 v = *(const float4*)&wemb[(size_t)sids[r] * EDIM + k4 * 4];
            *(float4*)&we_g[(size_t)(t0 + r) * EDIM + k4 * 4] = v;
        }
    }
    __syncthreads();
    for (int q = 0; q < 4; ++q) {
        int j = q * 256 + tid;
        int d = j >> 9, r = j & 511;
        const float* Wih = d ? cWih_b : cWih_f;
        const float* cb = d ? cb_b : cb_f;
        float b = cb[r];
        float acc[16];
#pragma unroll
        for (int tt = 0; tt < 16; ++tt) acc[tt] = b;
        for (int k4 = 0; k4 < 32; ++k4) {
            float4 wv = *(const float4*)&Wih[r * CEDIM + k4 * 4];
#pragma unroll
            for (int tt = 0; tt < 16; ++tt) {
                acc[tt] += wv.x * ceL[tt][k4 * 4 + 0] + wv.y * ceL[tt][k4 * 4 + 1]
                         + wv.z * ceL[tt][k4 * 4 + 2] + wv.w * ceL[tt][k4 * 4 + 3];
            }
        }
#pragma unroll
        for (int tt = 0; tt < 16; ++tt)
            cgx[((size_t)d * SQ + (t0 + tt)) * 512 + r] = acc[tt];
    }
}

// ---------------------------------------------------------------------------
// K2: blocks 0,1: char BiLSTM, ONE 1024-thread WG per direction, weights in
//     registers, 2 barriers/step, gx prefetch depth 2 (round-12 proven).
//     blocks 2+: GEMM wgx = we_g . wWih[:, :512]^T + wb
// ---------------------------------------------------------------------------
__global__ __launch_bounds__(1024, 4) void k2_charlstm_gemm(
    const float* __restrict__ cWhh_f, const float* __restrict__ cWhh_b,
    const float* __restrict__ cgx, float* __restrict__ cho,
    const float* __restrict__ we_g,
    const float* __restrict__ wWih_f, const float* __restrict__ wb_f,
    const float* __restrict__ wWih_b, const float* __restrict__ wb_b,
    float* __restrict__ wgx)
{
    const int tid = threadIdx.x;
    __shared__ __align__(16) float At[32][68];
    __shared__ __align__(16) float Bt[32][128];
    __shared__ __align__(16) float hstC[128];
    __shared__ float partC[2][516];

    if (blockIdx.x < 2) {
        const int dir = blockIdx.x;
        const float* Whh = dir ? cWhh_b : cWhh_f;
        const int row = tid & 511;        // gate*128 + unit
        const int half = tid >> 9;        // 0/1 -> h chunk [half*64, +64)
        const float4* wp = (const float4*)&Whh[(size_t)row * CHH + half * 64];
        float4 w0 = wp[0], w1 = wp[1], w2 = wp[2], w3 = wp[3];
        float4 w4 = wp[4], w5 = wp[5], w6 = wp[6], w7 = wp[7];
        float4 w8 = wp[8], w9 = wp[9], w10 = wp[10], w11 = wp[11];
        float4 w12 = wp[12], w13 = wp[13], w14 = wp[14], w15 = wp[15];
        PIN4(w0) PIN4(w1) PIN4(w2) PIN4(w3) PIN4(w4) PIN4(w5) PIN4(w6) PIN4(w7)
        PIN4(w8) PIN4(w9) PIN4(w10) PIN4(w11) PIN4(w12) PIN4(w13) PIN4(w14) PIN4(w15)

        const float* gxc = cgx + (size_t)dir * SQ * 512;
        float cst = 0.f;
        float gxp0 = 0.f, gxp1 = 0.f;
        if (tid < 512) {    // half==0 thread owns row=tid's gx
            gxp0 = gxc[(size_t)(dir ? (SQ - 1) : 0) * 512 + tid];
            gxp1 = gxc[(size_t)(dir ? (SQ - 2) : 1) * 512 + tid];
        }
        if (tid < 32) *(float4*)&hstC[tid * 4] = make_float4(0, 0, 0, 0);
        __syncthreads();
        for (int t = 0; t < SQ; ++t) {
            const int x = dir ? (SQ - 1 - t) : t;
            float gxv = gxp0;
            gxp0 = gxp1;
            if (tid < 512 && t + 2 < SQ) {
                const int x2 = dir ? (SQ - 3 - t) : (t + 2);
                gxp1 = gxc[(size_t)x2 * 512 + tid];
            }
            float a0 = 0.f, a1 = 0.f, a2 = 0.f, a3 = 0.f;
            const float* hc = &hstC[half * 64];
            FMA4(w0, 0)   FMA4(w1, 4)   FMA4(w2, 8)   FMA4(w3, 12)
            FMA4(w4, 16)  FMA4(w5, 20)  FMA4(w6, 24)  FMA4(w7, 28)
            FMA4(w8, 32)  FMA4(w9, 36)  FMA4(w10, 40) FMA4(w11, 44)
            FMA4(w12, 48) FMA4(w13, 52) FMA4(w14, 56) FMA4(w15, 60)
            float dot = (a0 + a1) + (a2 + a3);
            partC[half][row] = half ? dot : (dot + gxv);
            __syncthreads();
            if (tid < 128) {
                float siv = partC[0][tid]       + partC[1][tid];
                float sfv = partC[0][128 + tid] + partC[1][128 + tid];
                float sgv = partC[0][256 + tid] + partC[1][256 + tid];
                float sov = partC[0][384 + tid] + partC[1][384 + tid];
                float iv = sigf(siv), fv = sigf(sfv), ov = sigf(sov);
                float yg = sigf(sgv + sgv);
                float gv = yg + yg - 1.f;         // tanh(x) = 2*sig(2x)-1
                cst = fv * cst + iv * gv;
                float ts = sigf(cst + cst);
                float h = ov * (ts + ts - 1.f);
                hstC[tid] = h;
                cho[(size_t)x * 256 + dir * CHH + tid] = h;
            }
            __syncthreads();
        }
        return;
    }
    // ---------------- GEMM (word-emb part of word gx), 1024 threads ---------
    const int tile = blockIdx.x - 2;
    const int dir = tile >> 10;
    const int rem = tile & 1023;
    const int mb = rem >> 4;   // 64-row block of t
    const int nb = rem & 15;   // 128-col block of r
    const float* Wih = dir ? wWih_b : wWih_f;
    const float* wb = dir ? wb_b : wb_f;
    float* C = wgx + (size_t)dir * SQ * 2048;
    const int tm = tid >> 6, tn = tid & 63;   // tm wave-uniform -> A broadcast
    float acc[4][2];
#pragma unroll
    for (int i = 0; i < 4; ++i) { acc[i][0] = 0.f; acc[i][1] = 0.f; }
    for (int kb = 0; kb < 16; ++kb) {
        if (tid < 512) {
            int rowm = tid >> 3, k4 = tid & 7;
            float4 v = *(const float4*)&we_g[(size_t)(mb * 64 + rowm) * EDIM + kb * 32 + k4 * 4];
            At[k4 * 4 + 0][rowm] = v.x; At[k4 * 4 + 1][rowm] = v.y;
            At[k4 * 4 + 2][rowm] = v.z; At[k4 * 4 + 3][rowm] = v.w;
        }
        {
            int rr = tid >> 3, k4 = tid & 7;
            float4 v = *(const float4*)&Wih[(size_t)(nb * 128 + rr) * 768 + kb * 32 + k4 * 4];
            Bt[k4 * 4 + 0][rr] = v.x; Bt[k4 * 4 + 1][rr] = v.y;
            Bt[k4 * 4 + 2][rr] = v.z; Bt[k4 * 4 + 3][rr] = v.w;
        }
        __syncthreads();
#pragma unroll
        for (int kk = 0; kk < 32; ++kk) {
            float4 a4 = *(const float4*)&At[kk][tm * 4];
            float2 b2 = *(const float2*)&Bt[kk][tn * 2];
            acc[0][0] += a4.x * b2.x; acc[0][1] += a4.x * b2.y;
            acc[1][0] += a4.y * b2.x; acc[1][1] += a4.y * b2.y;
            acc[2][0] += a4.z * b2.x; acc[2][1] += a4.z * b2.y;
            acc[3][0] += a4.w * b2.x; acc[3][1] += a4.w * b2.y;
        }
        __syncthreads();
    }
    float2 wbv = *(const float2*)&wb[nb * 128 + tn * 2];
#pragma unroll
    for (int i = 0; i < 4; ++i) {
        float2 o;
        o.x = acc[i][0] + wbv.x; o.y = acc[i][1] + wbv.y;
        *(float2*)&C[(size_t)(mb * 64 + tm * 4 + i) * 2048 + nb * 128 + tn * 2] = o;
    }
}

// ---------------------------------------------------------------------------
// K3: wgx += char_out . wWih[:,512:768]^T
// ---------------------------------------------------------------------------
__global__ __launch_bounds__(512, 2) void k3_gemm_char(
    const float* __restrict__ cho,
    const float* __restrict__ wWih_f, const float* __restrict__ wWih_b,
    float* __restrict__ wgx)
{
    const int tid = threadIdx.x;
    const int tile = blockIdx.x;
    const int dir = tile >> 10;
    const int rem = tile & 1023;
    const int mb = rem >> 4, nb = rem & 15;
    const float* Wih = dir ? wWih_b : wWih_f;
    float* C = wgx + (size_t)dir * SQ * 2048;
    __shared__ __align__(16) float At[32][68];
    __shared__ __align__(16) float Bt[32][128];
    const int tm = tid >> 5, tn = tid & 31;
    float acc[4][4];
#pragma unroll
    for (int i = 0; i < 4; ++i)
#pragma unroll
        for (int jj = 0; jj < 4; ++jj) acc[i][jj] = 0.f;
    for (int kb = 0; kb < 8; ++kb) {
        {
            int rowm = tid >> 3, k4 = tid & 7;
            float4 v = *(const float4*)&cho[(size_t)(mb * 64 + rowm) * 256 + kb * 32 + k4 * 4];
            At[k4 * 4 + 0][rowm] = v.x; At[k4 * 4 + 1][rowm] = v.y;
            At[k4 * 4 + 2][rowm] = v.z; At[k4 * 4 + 3][rowm] = v.w;
        }
#pragma unroll
        for (int q = 0; q < 2; ++q) {
            int f4 = q * 512 + tid;
            int rr = f4 >> 3, k4 = f4 & 7;
            float4 v = *(const float4*)&Wih[(size_t)(nb * 128 + rr) * 768 + 512 + kb * 32 + k4 * 4];
            Bt[k4 * 4 + 0][rr] = v.x; Bt[k4 * 4 + 1][rr] = v.y;
            Bt[k4 * 4 + 2][rr] = v.z; Bt[k4 * 4 + 3][rr] = v.w;
        }
        __syncthreads();
#pragma unroll
        for (int kk = 0; kk < 32; ++kk) {
            float4 a4 = *(const float4*)&At[kk][tm * 4];
            float4 b4 = *(const float4*)&Bt[kk][tn * 4];
            acc[0][0] += a4.x * b4.x; acc[0][1] += a4.x * b4.y; acc[0][2] += a4.x * b4.z; acc[0][3] += a4.x * b4.w;
            acc[1][0] += a4.y * b4.x; acc[1][1] += a4.y * b4.y; acc[1][2] += a4.y * b4.z; acc[1][3] += a4.y * b4.w;
            acc[2][0] += a4.z * b4.x; acc[2][1] += a4.z * b4.y; acc[2][2] += a4.z * b4.z; acc[2][3] += a4.z * b4.w;
            acc[3][0] += a4.w * b4.x; acc[3][1] += a4.w * b4.y; acc[3][2] += a4.w * b4.z; acc[3][3] += a4.w * b4.w;
        }
        __syncthreads();
    }
#pragma unroll
    for (int i = 0; i < 4; ++i) {
        float* cp = &C[(size_t)(mb * 64 + tm * 4 + i) * 2048 + nb * 128 + tn * 4];
        float4 o = *(float4*)cp;
        o.x += acc[i][0]; o.y += acc[i][1]; o.z += acc[i][2]; o.w += acc[i][3];
        *(float4*)cp = o;
    }
}

// ---------------------------------------------------------------------------
// K4: word BiLSTM (round-11 proven structure). 32 WGs/direction x 1024
//     threads; wave0 batched poll+stage of tagged pairs; 2 barriers/step;
//     wave-parallel epilogue; lanes<16 publish. Fast path spins without
//     s_sleep (tighter detect); mirror fallback keeps sleep + timeout.
// ---------------------------------------------------------------------------
__global__ __launch_bounds__(1024, 4) void k4_word_lstm(
    const float* __restrict__ wWhh_f, const float* __restrict__ wWhh_b,
    const float* __restrict__ wgx, float* __restrict__ lstm, ull* __restrict__ pairs)
{
    const int res = blockIdx.x & 7;
    if (res > 1) return;
    const int dir = res;
    const int wid = blockIdx.x >> 3;      // 0..31
    const int tid = threadIdx.x;
    const int k = tid >> 6;               // h-chunk = wave id (0..15)
    const int r = tid & 63;               // g*16+u
    const int g = r >> 4, u = r & 15;
    const float* Whh = dir ? wWhh_b : wWhh_f;
    const int G = g * WH + wid * 16 + u;
    const float4* wp = (const float4*)&Whh[(size_t)G * WH + k * 32];
    float4 w0 = wp[0], w1 = wp[1], w2 = wp[2], w3 = wp[3];
    float4 w4 = wp[4], w5 = wp[5], w6 = wp[6], w7 = wp[7];
    PIN4(w0) PIN4(w1) PIN4(w2) PIN4(w3) PIN4(w4) PIN4(w5) PIN4(w6) PIN4(w7)

    __shared__ __align__(16) float hst[512];
    __shared__ float part[16][65];

    ull* wpf = pairs;            // [2][2][512] fast
    ull* wpm = pairs + 2048;     // mirror
    const float* gx = wgx + (size_t)dir * SQ * 2048;
    float cst = 0.f;
    int useFast = 1, alive = 1;
    for (int t = 0; t < SQ; ++t) {
        const int x = dir ? (SQ - 1 - t) : t;
        float gxv = 0.f;
        if (tid < 64)
            gxv = gx[(size_t)x * 2048 + (size_t)(tid >> 4) * 512 + wid * 16 + (tid & 15)];
        if (t == 0) {
            if (tid < 128) *(float4*)&hst[tid * 4] = make_float4(0, 0, 0, 0);
        } else if (tid < 64) {            // wave0: poll 8 pairs/lane + stage h
            const size_t boff = ((size_t)((t - 1) & 1) * 2 + dir) * 512 + tid * 8;
            const ull* pf = wpf + boff;
            const ull* pm = wpm + boff;
            ull q0 = 0, q1 = 0, q2 = 0, q3 = 0, q4 = 0, q5 = 0, q6 = 0, q7 = 0;
            int spins = 0;
            while (alive) {
                if (useFast) {
                    ld8x_sc0(pf, q0, q1, q2, q3, q4, q5, q6, q7);
                } else {
                    q0 = ld_mir(pm + 0); q1 = ld_mir(pm + 1);
                    q2 = ld_mir(pm + 2); q3 = ld_mir(pm + 3);
                    q4 = ld_mir(pm + 4); q5 = ld_mir(pm + 5);
                    q6 = ld_mir(pm + 6); q7 = ld_mir(pm + 7);
                }
                unsigned tm = umin2(umin2(umin2((unsigned)(q0 >> 32), (unsigned)(q1 >> 32)),
                                          umin2((unsigned)(q2 >> 32), (unsigned)(q3 >> 32))),
                                    umin2(umin2((unsigned)(q4 >> 32), (unsigned)(q5 >> 32)),
                                          umin2((unsigned)(q6 >> 32), (unsigned)(q7 >> 32))));
                if (__all(tm >= (unsigned)t)) break;
                ++spins;
                if (useFast) {
                    if (spins > 8192) { useFast = 0; spins = 0; }
                } else {
                    if (spins > (1 << 20)) alive = 0;
                    __builtin_amdgcn_s_sleep(1);
                }
            }
            float* hd = &hst[tid * 8];
            hd[0] = __uint_as_float((unsigned)q0); hd[1] = __uint_as_float((unsigned)q1);
            hd[2] = __uint_as_float((unsigned)q2); hd[3] = __uint_as_float((unsigned)q3);
            hd[4] = __uint_as_float((unsigned)q4); hd[5] = __uint_as_float((unsigned)q5);
            hd[6] = __uint_as_float((unsigned)q6); hd[7] = __uint_as_float((unsigned)q7);
        }
        __syncthreads();
        float a0 = 0.f, a1 = 0.f, a2 = 0.f, a3 = 0.f;
        const float* hc = &hst[k * 32];
        FMA4(w0, 0)  FMA4(w1, 4)  FMA4(w2, 8)  FMA4(w3, 12)
        FMA4(w4, 16) FMA4(w5, 20) FMA4(w6, 24) FMA4(w7, 28)
        part[k][r] = (a0 + a1) + (a2 + a3);
        __syncthreads();
        if (tid < 64) {
            float s = gxv;
#pragma unroll
            for (int kk = 0; kk < 16; ++kk) s += part[kk][tid];
            const bool isg = ((tid >> 4) == 2);
            float y = sigf(isg ? (s + s) : s);     // tanh(x) = 2*sig(2x)-1
            float val = isg ? (y + y - 1.f) : y;
            float fv = __shfl(val, 16 + (tid & 15));
            float gv = __shfl(val, 32 + (tid & 15));
            float ov = __shfl(val, 48 + (tid & 15));
            if (tid < 16) {
                cst = fv * cst + val * gv;         // val = i-gate (lanes 0..15)
                float ts = sigf(cst + cst);
                float h = ov * (ts + ts - 1.f);
                const int unit = wid * 16 + tid;
                lstm[(size_t)x * 1024 + dir * WH + unit] = h;
                ull q = ((ull)(unsigned)(t + 1) << 32) | (ull)__float_as_uint(h);
                const size_t poff = ((size_t)(t & 1) * 2 + dir) * 512 + unit;
                st_plain8(wpf + poff, q);
                st_mir(wpm + poff, q);
            }
        }
    }
}

// ---------------------------------------------------------------------------
// K5: emissions = lstm_out @ W_tag^T + b_tag
// ---------------------------------------------------------------------------
__global__ __launch_bounds__(64) void k5_emis(
    const float* __restrict__ lstm, const float* __restrict__ Wtag,
    const float* __restrict__ btag, float* __restrict__ emis)
{
    const int t = blockIdx.x, tid = threadIdx.x;
    __shared__ __align__(16) float rowL[1024];
#pragma unroll
    for (int q = 0; q < 4; ++q) {
        int f4 = q * 64 + tid;
        *(float4*)&rowL[f4 * 4] = *(const float4*)&lstm[(size_t)t * 1024 + f4 * 4];
    }
    __syncthreads();
    if (tid < NT) {
        float a0 = 0.f, a1 = 0.f, a2 = 0.f, a3 = 0.f;
        const float* wr = Wtag + (size_t)tid * 1024;
        for (int k4 = 0; k4 < 256; ++k4) {
            float4 wv = *(const float4*)&wr[k4 * 4];
            a0 += wv.x * rowL[k4 * 4 + 0];
            a1 += wv.y * rowL[k4 * 4 + 1];
            a2 += wv.z * rowL[k4 * 4 + 2];
            a3 += wv.w * rowL[k4 * 4 + 3];
        }
        emis[(size_t)t * NT + tid] = btag[tid] + (a0 + a1) + (a2 + a3);
    }
}

// ---------------------------------------------------------------------------
// K6a: Viterbi forward (sequential)
// ---------------------------------------------------------------------------
__global__ __launch_bounds__(256) void k6a_viterbi(
    const float* __restrict__ emis, const float* __restrict__ start_t,
    const float* __restrict__ end_t, const float* __restrict__ trans,
    unsigned char* __restrict__ bpb, int* __restrict__ last)
{
    const int tid = threadIdx.x;
    const int g = tid >> 6, c = tid & 63;
    __shared__ float sc[64];
    __shared__ float pbest[4][64];
    __shared__ int pbp[4][64];
    const int p0 = g * 13;
    float tr[13];
#pragma unroll
    for (int i = 0; i < 13; ++i) {
        int p = p0 + i;
        tr[i] = (c < NT && p < NT) ? trans[p * NT + c] : -1e30f;
    }
    if (tid < 64) sc[tid] = (tid < NT) ? (start_t[tid] + emis[tid]) : -1e30f;
    __syncthreads();
    for (int t = 1; t < SQ; ++t) {
        float best = -1e30f; int bp = 0;
#pragma unroll
        for (int i = 0; i < 13; ++i) {
            float v = sc[p0 + i] + tr[i];
            if (v > best) { best = v; bp = p0 + i; }
        }
        pbest[g][c] = best; pbp[g][c] = bp;
        __syncthreads();
        if (tid < NT) {
            float b = pbest[0][tid]; int bb = pbp[0][tid];
#pragma unroll
            for (int gg = 1; gg < 4; ++gg) {
                float v = pbest[gg][tid];
                if (v > b) { b = v; bb = pbp[gg][tid]; }
            }
            bpb[(size_t)t * NT + tid] = (unsigned char)bb;
            sc[tid] = b + emis[(size_t)t * NT + tid];
        }
        __syncthreads();
    }
    if (tid == 0) {
        float b = -1e30f; int bi = 0;
        for (int cc = 0; cc < NT; ++cc) {
            float v = sc[cc] + end_t[cc];
            if (v > b) { b = v; bi = cc; }
        }
        *last = bi;
    }
}

// K6b: per-chunk end-tag -> end-of-previous-chunk-tag maps
__global__ __launch_bounds__(64) void k6b_maps(
    const unsigned char* __restrict__ bpb, int* __restrict__ map_)
{
    const int k = blockIdx.x;
    const int e = threadIdx.x;
    if (k == 0 || e >= NT) return;
    int tag = e;
    for (int i = 63; i >= 0; --i) {
        int t = k * 64 + i;
        tag = bpb[(size_t)t * NT + tag];
    }
    map_[k * NT + e] = tag;
}

// K6c: stitch chunk boundary tags, emit path
__global__ __launch_bounds__(64) void k6c_backtrack(
    const unsigned char* __restrict__ bpb, const int* __restrict__ map_,
    const int* __restrict__ last, int* __restrict__ path)
{
    __shared__ int B[64];
    if (threadIdx.x == 0) {
        int tag = *last;
        B[63] = tag;
        for (int k = 63; k >= 1; --k) {
            tag = map_[k * NT + tag];
            B[k - 1] = tag;
        }
    }
    __syncthreads();
    const int k = threadIdx.x;
    int tag = B[k];
    for (int i = 63; i >= 0; --i) {
        int t = k * 64 + i;
        path[t] = tag;
        if (t >= 1) tag = bpb[(size_t)t * NT + tag];
    }
}

// ---------------------------------------------------------------------------
extern "C" void kernel_launch(void* const* d_in, const int* in_sizes, int n_in,
                              void* d_out, int out_size, void* d_ws, size_t ws_size,
                              hipStream_t stream)
{
    const int* sent = (const int*)d_in[0];
    const int* csent = (const int*)d_in[1];
    const float* wemb = (const float*)d_in[2];
    const float* cemb = (const float*)d_in[3];
    const float* cWih_f = (const float*)d_in[4];
    const float* cWhh_f = (const float*)d_in[5];
    const float* cb_f = (const float*)d_in[6];
    const float* cWih_b = (const float*)d_in[7];
    const float* cWhh_b = (const float*)d_in[8];
    const float* cb_b = (const float*)d_in[9];
    const float* wWih_f = (const float*)d_in[10];
    const float* wWhh_f = (const float*)d_in[11];
    const float* wb_f = (const float*)d_in[12];
    const float* wWih_b = (const float*)d_in[13];
    const float* wWhh_b = (const float*)d_in[14];
    const float* wb_b = (const float*)d_in[15];
    const float* Wtag = (const float*)d_in[16];
    const float* btag = (const float*)d_in[17];
    const float* start_t = (const float*)d_in[18];
    const float* end_t = (const float*)d_in[19];
    const float* trans = (const float*)d_in[20];
    int* path = (int*)d_out;

    float* ws = (float*)d_ws;
    float* we_g = ws;                                   // SQ*EDIM
    float* cgx  = we_g + (size_t)SQ * EDIM;             // 2*SQ*512
    float* cho  = cgx + (size_t)2 * SQ * 512;           // SQ*256
    float* wgx  = cho + (size_t)SQ * 256;               // 2*SQ*2048
    float* lstm = wgx + (size_t)2 * SQ * 2048;          // SQ*1024
    float* emis = lstm + (size_t)SQ * 1024;             // SQ*NT
    ull* pairs  = (ull*)(emis + (size_t)SQ * NT);       // 5120 ulongs (40KB)
    int* map_   = (int*)(pairs + 5120);                 // 64*NT
    int* lastp  = map_ + 64 * NT;                       // 1 (+pad)
    unsigned char* bpb = (unsigned char*)(lastp + 4);   // SQ*NT bytes

    (void)hipMemsetAsync(pairs, 0, 5120 * sizeof(ull), stream);

    k1_gather_cgx<<<SQ / 16, 256, 0, stream>>>(sent, csent, wemb, cemb,
                                               cWih_f, cb_f, cWih_b, cb_b, we_g, cgx);
    k2_charlstm_gemm<<<2 + 2048, 1024, 0, stream>>>(cWhh_f, cWhh_b, cgx, cho, we_g,
                                                    wWih_f, wb_f, wWih_b, wb_b, wgx);
    k3_gemm_char<<<2048, 512, 0, stream>>>(cho, wWih_f, wWih_b, wgx);
    k4_word_lstm<<<256, 1024, 0, stream>>>(wWhh_f, wWhh_b, wgx, lstm, pairs);
    k5_emis<<<SQ, 64, 0, stream>>>(lstm, Wtag, btag, emis);
    k6a_viterbi<<<1, 256, 0, stream>>>(emis, start_t, end_t, trans, bpb, lastp);
    k6b_maps<<<64, 64, 0, stream>>>(bpb, map_);
    k6c_backtrack<<<1, 64, 0, stream>>>(bpb, map_, lastp, path);
}

// Round 15
// 14650.566 us; speedup vs baseline: 1.1249x; 1.1249x over previous
//
#include <hip/hip_runtime.h>
#include <math.h>

#define SQ   4096
#define EDIM 512
#define CEDIM 128
#define CHH  128
#define WH   512
#define NT   50

typedef unsigned long long ull;

__device__ __forceinline__ float sigf(float x) { return 1.0f / (1.0f + expf(-x)); }

#define PIN4(V) asm volatile("" : "+v"(V.x), "+v"(V.y), "+v"(V.z), "+v"(V.w));

// ---- tagged-pair helpers (proven recipe) -------------------------------------
__device__ __forceinline__ void ld8x_sc0(const ull* p, ull& q0, ull& q1, ull& q2,
                                         ull& q3, ull& q4, ull& q5, ull& q6, ull& q7) {
    asm volatile("global_load_dwordx2 %0, %8, off sc0\n\t"
                 "global_load_dwordx2 %1, %8, off offset:8 sc0\n\t"
                 "global_load_dwordx2 %2, %8, off offset:16 sc0\n\t"
                 "global_load_dwordx2 %3, %8, off offset:24 sc0\n\t"
                 "global_load_dwordx2 %4, %8, off offset:32 sc0\n\t"
                 "global_load_dwordx2 %5, %8, off offset:40 sc0\n\t"
                 "global_load_dwordx2 %6, %8, off offset:48 sc0\n\t"
                 "global_load_dwordx2 %7, %8, off offset:56 sc0\n\t"
                 "s_waitcnt vmcnt(0)"
                 : "=&v"(q0), "=&v"(q1), "=&v"(q2), "=&v"(q3),
                   "=&v"(q4), "=&v"(q5), "=&v"(q6), "=&v"(q7)
                 : "v"(p) : "memory");
}
__device__ __forceinline__ ull ld_mir(const ull* p) {
    return __hip_atomic_load(p, __ATOMIC_RELAXED, __HIP_MEMORY_SCOPE_AGENT);
}
__device__ __forceinline__ void st_plain8(ull* p, ull v) {
    asm volatile("global_store_dwordx2 %0, %1, off" :: "v"(p), "v"(v) : "memory");
}
__device__ __forceinline__ void st_mir(ull* p, ull v) {
    __hip_atomic_store(p, v, __ATOMIC_RELAXED, __HIP_MEMORY_SCOPE_AGENT);
}
__device__ __forceinline__ unsigned umin2(unsigned a, unsigned b) { return a < b ? a : b; }

#define FMA4(W, off) { float4 h4 = *(const float4*)&hc[off]; \
    a0 += W.x * h4.x; a1 += W.y * h4.y; a2 += W.z * h4.z; a3 += W.w * h4.w; }

// ---------------------------------------------------------------------------
// K1: gather word/char embedding rows; compute char-LSTM input GEMM
// ---------------------------------------------------------------------------
__global__ __launch_bounds__(256) void k1_gather_cgx(
    const int* __restrict__ sent, const int* __restrict__ csent,
    const float* __restrict__ wemb, const float* __restrict__ cemb,
    const float* __restrict__ cWih_f, const float* __restrict__ cb_f,
    const float* __restrict__ cWih_b, const float* __restrict__ cb_b,
    float* __restrict__ we_g, float* __restrict__ cgx)
{
    const int tid = threadIdx.x;
    const int t0 = blockIdx.x * 16;
    __shared__ __align__(16) float ceL[16][128];
    __shared__ int sids[16], cids[16];
    if (tid < 16) sids[tid] = sent[t0 + tid];
    else if (tid < 32) cids[tid - 16] = csent[t0 + tid - 16];
    __syncthreads();
    {
        int f4 = tid;
        for (int q = 0; q < 2; ++q, f4 += 256) {
            int r = f4 >> 5, k4 = f4 & 31;
            float4 v = *(const float4*)&cemb[(size_t)cids[r] * CEDIM + k4 * 4];
            *(float4*)&ceL[r][k4 * 4] = v;
        }
    }
    {
        int f4 = tid;
        for (int q = 0; q < 8; ++q, f4 += 256) {
            int r = f4 >> 7, k4 = f4 & 127;
            float4 v = *(const float4*)&wemb[(size_t)sids[r] * EDIM + k4 * 4];
            *(float4*)&we_g[(size_t)(t0 + r) * EDIM + k4 * 4] = v;
        }
    }
    __syncthreads();
    for (int q = 0; q < 4; ++q) {
        int j = q * 256 + tid;
        int d = j >> 9, r = j & 511;
        const float* Wih = d ? cWih_b : cWih_f;
        const float* cb = d ? cb_b : cb_f;
        float b = cb[r];
        float acc[16];
#pragma unroll
        for (int tt = 0; tt < 16; ++tt) acc[tt] = b;
        for (int k4 = 0; k4 < 32; ++k4) {
            float4 wv = *(const float4*)&Wih[r * CEDIM + k4 * 4];
#pragma unroll
            for (int tt = 0; tt < 16; ++tt) {
                acc[tt] += wv.x * ceL[tt][k4 * 4 + 0] + wv.y * ceL[tt][k4 * 4 + 1]
                         + wv.z * ceL[tt][k4 * 4 + 2] + wv.w * ceL[tt][k4 * 4 + 3];
            }
        }
#pragma unroll
        for (int tt = 0; tt < 16; ++tt)
            cgx[((size_t)d * SQ + (t0 + tt)) * 512 + r] = acc[tt];
    }
}

// ---------------------------------------------------------------------------
// K2: blocks 0,1: char BiLSTM, ONE 1024-thread WG per direction, weights in
//     registers, 2 barriers/step, gx prefetch depth 2.
//     blocks 2+: GEMM wgx = we_g . wWih[:, :512]^T + wb
// ---------------------------------------------------------------------------
__global__ __launch_bounds__(1024, 4) void k2_charlstm_gemm(
    const float* __restrict__ cWhh_f, const float* __restrict__ cWhh_b,
    const float* __restrict__ cgx, float* __restrict__ cho,
    const float* __restrict__ we_g,
    const float* __restrict__ wWih_f, const float* __restrict__ wb_f,
    const float* __restrict__ wWih_b, const float* __restrict__ wb_b,
    float* __restrict__ wgx)
{
    const int tid = threadIdx.x;
    __shared__ __align__(16) float At[32][68];
    __shared__ __align__(16) float Bt[32][128];
    __shared__ __align__(16) float hstC[128];
    __shared__ float partC[2][516];

    if (blockIdx.x < 2) {
        const int dir = blockIdx.x;
        const float* Whh = dir ? cWhh_b : cWhh_f;
        const int row = tid & 511;        // gate*128 + unit
        const int half = tid >> 9;        // 0/1 -> h chunk [half*64, +64)
        const float4* wp = (const float4*)&Whh[(size_t)row * CHH + half * 64];
        float4 w0 = wp[0], w1 = wp[1], w2 = wp[2], w3 = wp[3];
        float4 w4 = wp[4], w5 = wp[5], w6 = wp[6], w7 = wp[7];
        float4 w8 = wp[8], w9 = wp[9], w10 = wp[10], w11 = wp[11];
        float4 w12 = wp[12], w13 = wp[13], w14 = wp[14], w15 = wp[15];
        PIN4(w0) PIN4(w1) PIN4(w2) PIN4(w3) PIN4(w4) PIN4(w5) PIN4(w6) PIN4(w7)
        PIN4(w8) PIN4(w9) PIN4(w10) PIN4(w11) PIN4(w12) PIN4(w13) PIN4(w14) PIN4(w15)

        const float* gxc = cgx + (size_t)dir * SQ * 512;
        float cst = 0.f;
        float gxp0 = 0.f, gxp1 = 0.f;
        if (tid < 512) {    // half==0 thread owns row=tid's gx
            gxp0 = gxc[(size_t)(dir ? (SQ - 1) : 0) * 512 + tid];
            gxp1 = gxc[(size_t)(dir ? (SQ - 2) : 1) * 512 + tid];
        }
        if (tid < 32) *(float4*)&hstC[tid * 4] = make_float4(0, 0, 0, 0);
        __syncthreads();
        for (int t = 0; t < SQ; ++t) {
            const int x = dir ? (SQ - 1 - t) : t;
            float gxv = gxp0;
            gxp0 = gxp1;
            if (tid < 512 && t + 2 < SQ) {
                const int x2 = dir ? (SQ - 3 - t) : (t + 2);
                gxp1 = gxc[(size_t)x2 * 512 + tid];
            }
            float a0 = 0.f, a1 = 0.f, a2 = 0.f, a3 = 0.f;
            const float* hc = &hstC[half * 64];
            FMA4(w0, 0)   FMA4(w1, 4)   FMA4(w2, 8)   FMA4(w3, 12)
            FMA4(w4, 16)  FMA4(w5, 20)  FMA4(w6, 24)  FMA4(w7, 28)
            FMA4(w8, 32)  FMA4(w9, 36)  FMA4(w10, 40) FMA4(w11, 44)
            FMA4(w12, 48) FMA4(w13, 52) FMA4(w14, 56) FMA4(w15, 60)
            float dot = (a0 + a1) + (a2 + a3);
            partC[half][row] = half ? dot : (dot + gxv);
            __syncthreads();
            if (tid < 128) {
                float siv = partC[0][tid]       + partC[1][tid];
                float sfv = partC[0][128 + tid] + partC[1][128 + tid];
                float sgv = partC[0][256 + tid] + partC[1][256 + tid];
                float sov = partC[0][384 + tid] + partC[1][384 + tid];
                float iv = sigf(siv), fv = sigf(sfv), ov = sigf(sov);
                float yg = sigf(sgv + sgv);
                float gv = yg + yg - 1.f;         // tanh(x) = 2*sig(2x)-1
                cst = fv * cst + iv * gv;
                float ts = sigf(cst + cst);
                float h = ov * (ts + ts - 1.f);
                hstC[tid] = h;
                cho[(size_t)x * 256 + dir * CHH + tid] = h;
            }
            __syncthreads();
        }
        return;
    }
    // ---------------- GEMM (word-emb part of word gx), 1024 threads ---------
    const int tile = blockIdx.x - 2;
    const int dir = tile >> 10;
    const int rem = tile & 1023;
    const int mb = rem >> 4;   // 64-row block of t
    const int nb = rem & 15;   // 128-col block of r
    const float* Wih = dir ? wWih_b : wWih_f;
    const float* wb = dir ? wb_b : wb_f;
    float* C = wgx + (size_t)dir * SQ * 2048;
    const int tm = tid >> 6, tn = tid & 63;   // tm wave-uniform -> A broadcast
    float acc[4][2];
#pragma unroll
    for (int i = 0; i < 4; ++i) { acc[i][0] = 0.f; acc[i][1] = 0.f; }
    for (int kb = 0; kb < 16; ++kb) {
        if (tid < 512) {
            int rowm = tid >> 3, k4 = tid & 7;
            float4 v = *(const float4*)&we_g[(size_t)(mb * 64 + rowm) * EDIM + kb * 32 + k4 * 4];
            At[k4 * 4 + 0][rowm] = v.x; At[k4 * 4 + 1][rowm] = v.y;
            At[k4 * 4 + 2][rowm] = v.z; At[k4 * 4 + 3][rowm] = v.w;
        }
        {
            int rr = tid >> 3, k4 = tid & 7;
            float4 v = *(const float4*)&Wih[(size_t)(nb * 128 + rr) * 768 + kb * 32 + k4 * 4];
            Bt[k4 * 4 + 0][rr] = v.x; Bt[k4 * 4 + 1][rr] = v.y;
            Bt[k4 * 4 + 2][rr] = v.z; Bt[k4 * 4 + 3][rr] = v.w;
        }
        __syncthreads();
#pragma unroll
        for (int kk = 0; kk < 32; ++kk) {
            float4 a4 = *(const float4*)&At[kk][tm * 4];
            float2 b2 = *(const float2*)&Bt[kk][tn * 2];
            acc[0][0] += a4.x * b2.x; acc[0][1] += a4.x * b2.y;
            acc[1][0] += a4.y * b2.x; acc[1][1] += a4.y * b2.y;
            acc[2][0] += a4.z * b2.x; acc[2][1] += a4.z * b2.y;
            acc[3][0] += a4.w * b2.x; acc[3][1] += a4.w * b2.y;
        }
        __syncthreads();
    }
    float2 wbv = *(const float2*)&wb[nb * 128 + tn * 2];
#pragma unroll
    for (int i = 0; i < 4; ++i) {
        float2 o;
        o.x = acc[i][0] + wbv.x; o.y = acc[i][1] + wbv.y;
        *(float2*)&C[(size_t)(mb * 64 + tm * 4 + i) * 2048 + nb * 128 + tn * 2] = o;
    }
}

// ---------------------------------------------------------------------------
// K3: wgx += char_out . wWih[:,512:768]^T
// ---------------------------------------------------------------------------
__global__ __launch_bounds__(512, 2) void k3_gemm_char(
    const float* __restrict__ cho,
    const float* __restrict__ wWih_f, const float* __restrict__ wWih_b,
    float* __restrict__ wgx)
{
    const int tid = threadIdx.x;
    const int tile = blockIdx.x;
    const int dir = tile >> 10;
    const int rem = tile & 1023;
    const int mb = rem >> 4, nb = rem & 15;
    const float* Wih = dir ? wWih_b : wWih_f;
    float* C = wgx + (size_t)dir * SQ * 2048;
    __shared__ __align__(16) float At[32][68];
    __shared__ __align__(16) float Bt[32][128];
    const int tm = tid >> 5, tn = tid & 31;
    float acc[4][4];
#pragma unroll
    for (int i = 0; i < 4; ++i)
#pragma unroll
        for (int jj = 0; jj < 4; ++jj) acc[i][jj] = 0.f;
    for (int kb = 0; kb < 8; ++kb) {
        {
            int rowm = tid >> 3, k4 = tid & 7;
            float4 v = *(const float4*)&cho[(size_t)(mb * 64 + rowm) * 256 + kb * 32 + k4 * 4];
            At[k4 * 4 + 0][rowm] = v.x; At[k4 * 4 + 1][rowm] = v.y;
            At[k4 * 4 + 2][rowm] = v.z; At[k4 * 4 + 3][rowm] = v.w;
        }
#pragma unroll
        for (int q = 0; q < 2; ++q) {
            int f4 = q * 512 + tid;
            int rr = f4 >> 3, k4 = f4 & 7;
            float4 v = *(const float4*)&Wih[(size_t)(nb * 128 + rr) * 768 + 512 + kb * 32 + k4 * 4];
            Bt[k4 * 4 + 0][rr] = v.x; Bt[k4 * 4 + 1][rr] = v.y;
            Bt[k4 * 4 + 2][rr] = v.z; Bt[k4 * 4 + 3][rr] = v.w;
        }
        __syncthreads();
#pragma unroll
        for (int kk = 0; kk < 32; ++kk) {
            float4 a4 = *(const float4*)&At[kk][tm * 4];
            float4 b4 = *(const float4*)&Bt[kk][tn * 4];
            acc[0][0] += a4.x * b4.x; acc[0][1] += a4.x * b4.y; acc[0][2] += a4.x * b4.z; acc[0][3] += a4.x * b4.w;
            acc[1][0] += a4.y * b4.x; acc[1][1] += a4.y * b4.y; acc[1][2] += a4.y * b4.z; acc[1][3] += a4.y * b4.w;
            acc[2][0] += a4.z * b4.x; acc[2][1] += a4.z * b4.y; acc[2][2] += a4.z * b4.z; acc[2][3] += a4.z * b4.w;
            acc[3][0] += a4.w * b4.x; acc[3][1] += a4.w * b4.y; acc[3][2] += a4.w * b4.z; acc[3][3] += a4.w * b4.w;
        }
        __syncthreads();
    }
#pragma unroll
    for (int i = 0; i < 4; ++i) {
        float* cp = &C[(size_t)(mb * 64 + tm * 4 + i) * 2048 + nb * 128 + tn * 4];
        float4 o = *(float4*)cp;
        o.x += acc[i][0]; o.y += acc[i][1]; o.z += acc[i][2]; o.w += acc[i][3];
        *(float4*)cp = o;
    }
}

// ---------------------------------------------------------------------------
// K4: word BiLSTM (round-11 proven structure, verbatim). 32 WGs/direction x
//     1024 threads; wave0 batched poll+stage of tagged pairs with s_sleep(1)
//     back-off (load-bearing: prevents L2 poll contention); 2 barriers/step;
//     wave-parallel epilogue; lanes<16 publish fast+mirror.
// ---------------------------------------------------------------------------
__global__ __launch_bounds__(1024, 4) void k4_word_lstm(
    const float* __restrict__ wWhh_f, const float* __restrict__ wWhh_b,
    const float* __restrict__ wgx, float* __restrict__ lstm, ull* __restrict__ pairs)
{
    const int res = blockIdx.x & 7;
    if (res > 1) return;
    const int dir = res;
    const int wid = blockIdx.x >> 3;      // 0..31
    const int tid = threadIdx.x;
    const int k = tid >> 6;               // h-chunk = wave id (0..15)
    const int r = tid & 63;               // g*16+u
    const int g = r >> 4, u = r & 15;
    const float* Whh = dir ? wWhh_b : wWhh_f;
    const int G = g * WH + wid * 16 + u;
    const float4* wp = (const float4*)&Whh[(size_t)G * WH + k * 32];
    float4 w0 = wp[0], w1 = wp[1], w2 = wp[2], w3 = wp[3];
    float4 w4 = wp[4], w5 = wp[5], w6 = wp[6], w7 = wp[7];
    PIN4(w0) PIN4(w1) PIN4(w2) PIN4(w3) PIN4(w4) PIN4(w5) PIN4(w6) PIN4(w7)

    __shared__ __align__(16) float hst[512];
    __shared__ float part[16][65];

    ull* wpf = pairs;            // [2][2][512] fast
    ull* wpm = pairs + 2048;     // mirror
    const float* gx = wgx + (size_t)dir * SQ * 2048;
    float cst = 0.f;
    int useFast = 1, alive = 1;
    for (int t = 0; t < SQ; ++t) {
        const int x = dir ? (SQ - 1 - t) : t;
        float gxv = 0.f;
        if (tid < 64)
            gxv = gx[(size_t)x * 2048 + (size_t)(tid >> 4) * 512 + wid * 16 + (tid & 15)];
        if (t == 0) {
            if (tid < 128) *(float4*)&hst[tid * 4] = make_float4(0, 0, 0, 0);
        } else if (tid < 64) {            // wave0: poll 8 pairs/lane + stage h
            const size_t boff = ((size_t)((t - 1) & 1) * 2 + dir) * 512 + tid * 8;
            const ull* pf = wpf + boff;
            const ull* pm = wpm + boff;
            ull q0 = 0, q1 = 0, q2 = 0, q3 = 0, q4 = 0, q5 = 0, q6 = 0, q7 = 0;
            int spins = 0;
            while (alive) {
                if (useFast) {
                    ld8x_sc0(pf, q0, q1, q2, q3, q4, q5, q6, q7);
                } else {
                    q0 = ld_mir(pm + 0); q1 = ld_mir(pm + 1);
                    q2 = ld_mir(pm + 2); q3 = ld_mir(pm + 3);
                    q4 = ld_mir(pm + 4); q5 = ld_mir(pm + 5);
                    q6 = ld_mir(pm + 6); q7 = ld_mir(pm + 7);
                }
                unsigned tm = umin2(umin2(umin2((unsigned)(q0 >> 32), (unsigned)(q1 >> 32)),
                                          umin2((unsigned)(q2 >> 32), (unsigned)(q3 >> 32))),
                                    umin2(umin2((unsigned)(q4 >> 32), (unsigned)(q5 >> 32)),
                                          umin2((unsigned)(q6 >> 32), (unsigned)(q7 >> 32))));
                if (__all(tm >= (unsigned)t)) break;
                ++spins;
                if (useFast && spins > 2048) { useFast = 0; spins = 0; }
                if (!useFast && spins > (1 << 20)) alive = 0;
                __builtin_amdgcn_s_sleep(1);
            }
            float* hd = &hst[tid * 8];
            hd[0] = __uint_as_float((unsigned)q0); hd[1] = __uint_as_float((unsigned)q1);
            hd[2] = __uint_as_float((unsigned)q2); hd[3] = __uint_as_float((unsigned)q3);
            hd[4] = __uint_as_float((unsigned)q4); hd[5] = __uint_as_float((unsigned)q5);
            hd[6] = __uint_as_float((unsigned)q6); hd[7] = __uint_as_float((unsigned)q7);
        }
        __syncthreads();
        float a0 = 0.f, a1 = 0.f, a2 = 0.f, a3 = 0.f;
        const float* hc = &hst[k * 32];
        FMA4(w0, 0)  FMA4(w1, 4)  FMA4(w2, 8)  FMA4(w3, 12)
        FMA4(w4, 16) FMA4(w5, 20) FMA4(w6, 24) FMA4(w7, 28)
        part[k][r] = (a0 + a1) + (a2 + a3);
        __syncthreads();
        if (tid < 64) {
            float s = gxv;
#pragma unroll
            for (int kk = 0; kk < 16; ++kk) s += part[kk][tid];
            const bool isg = ((tid >> 4) == 2);
            float y = sigf(isg ? (s + s) : s);     // tanh(x) = 2*sig(2x)-1
            float val = isg ? (y + y - 1.f) : y;
            float fv = __shfl(val, 16 + (tid & 15));
            float gv = __shfl(val, 32 + (tid & 15));
            float ov = __shfl(val, 48 + (tid & 15));
            if (tid < 16) {
                cst = fv * cst + val * gv;         // val = i-gate (lanes 0..15)
                float ts = sigf(cst + cst);
                float h = ov * (ts + ts - 1.f);
                const int unit = wid * 16 + tid;
                lstm[(size_t)x * 1024 + dir * WH + unit] = h;
                ull q = ((ull)(unsigned)(t + 1) << 32) | (ull)__float_as_uint(h);
                const size_t poff = ((size_t)(t & 1) * 2 + dir) * 512 + unit;
                st_plain8(wpf + poff, q);
                st_mir(wpm + poff, q);
            }
        }
    }
}

// ---------------------------------------------------------------------------
// K5: emissions = lstm_out @ W_tag^T + b_tag
// ---------------------------------------------------------------------------
__global__ __launch_bounds__(64) void k5_emis(
    const float* __restrict__ lstm, const float* __restrict__ Wtag,
    const float* __restrict__ btag, float* __restrict__ emis)
{
    const int t = blockIdx.x, tid = threadIdx.x;
    __shared__ __align__(16) float rowL[1024];
#pragma unroll
    for (int q = 0; q < 4; ++q) {
        int f4 = q * 64 + tid;
        *(float4*)&rowL[f4 * 4] = *(const float4*)&lstm[(size_t)t * 1024 + f4 * 4];
    }
    __syncthreads();
    if (tid < NT) {
        float a0 = 0.f, a1 = 0.f, a2 = 0.f, a3 = 0.f;
        const float* wr = Wtag + (size_t)tid * 1024;
        for (int k4 = 0; k4 < 256; ++k4) {
            float4 wv = *(const float4*)&wr[k4 * 4];
            a0 += wv.x * rowL[k4 * 4 + 0];
            a1 += wv.y * rowL[k4 * 4 + 1];
            a2 += wv.z * rowL[k4 * 4 + 2];
            a3 += wv.w * rowL[k4 * 4 + 3];
        }
        emis[(size_t)t * NT + tid] = btag[tid] + (a0 + a1) + (a2 + a3);
    }
}

// ---------------------------------------------------------------------------
// K6a: Viterbi forward (sequential)
// ---------------------------------------------------------------------------
__global__ __launch_bounds__(256) void k6a_viterbi(
    const float* __restrict__ emis, const float* __restrict__ start_t,
    const float* __restrict__ end_t, const float* __restrict__ trans,
    unsigned char* __restrict__ bpb, int* __restrict__ last)
{
    const int tid = threadIdx.x;
    const int g = tid >> 6, c = tid & 63;
    __shared__ float sc[64];
    __shared__ float pbest[4][64];
    __shared__ int pbp[4][64];
    const int p0 = g * 13;
    float tr[13];
#pragma unroll
    for (int i = 0; i < 13; ++i) {
        int p = p0 + i;
        tr[i] = (c < NT && p < NT) ? trans[p * NT + c] : -1e30f;
    }
    if (tid < 64) sc[tid] = (tid < NT) ? (start_t[tid] + emis[tid]) : -1e30f;
    __syncthreads();
    for (int t = 1; t < SQ; ++t) {
        float best = -1e30f; int bp = 0;
#pragma unroll
        for (int i = 0; i < 13; ++i) {
            float v = sc[p0 + i] + tr[i];
            if (v > best) { best = v; bp = p0 + i; }
        }
        pbest[g][c] = best; pbp[g][c] = bp;
        __syncthreads();
        if (tid < NT) {
            float b = pbest[0][tid]; int bb = pbp[0][tid];
#pragma unroll
            for (int gg = 1; gg < 4; ++gg) {
                float v = pbest[gg][tid];
                if (v > b) { b = v; bb = pbp[gg][tid]; }
            }
            bpb[(size_t)t * NT + tid] = (unsigned char)bb;
            sc[tid] = b + emis[(size_t)t * NT + tid];
        }
        __syncthreads();
    }
    if (tid == 0) {
        float b = -1e30f; int bi = 0;
        for (int cc = 0; cc < NT; ++cc) {
            float v = sc[cc] + end_t[cc];
            if (v > b) { b = v; bi = cc; }
        }
        *last = bi;
    }
}

// K6b: per-chunk end-tag -> end-of-previous-chunk-tag maps
__global__ __launch_bounds__(64) void k6b_maps(
    const unsigned char* __restrict__ bpb, int* __restrict__ map_)
{
    const int k = blockIdx.x;
    const int e = threadIdx.x;
    if (k == 0 || e >= NT) return;
    int tag = e;
    for (int i = 63; i >= 0; --i) {
        int t = k * 64 + i;
        tag = bpb[(size_t)t * NT + tag];
    }
    map_[k * NT + e] = tag;
}

// K6c: stitch chunk boundary tags, emit path
__global__ __launch_bounds__(64) void k6c_backtrack(
    const unsigned char* __restrict__ bpb, const int* __restrict__ map_,
    const int* __restrict__ last, int* __restrict__ path)
{
    __shared__ int B[64];
    if (threadIdx.x == 0) {
        int tag = *last;
        B[63] = tag;
        for (int k = 63; k >= 1; --k) {
            tag = map_[k * NT + tag];
            B[k - 1] = tag;
        }
    }
    __syncthreads();
    const int k = threadIdx.x;
    int tag = B[k];
    for (int i = 63; i >= 0; --i) {
        int t = k * 64 + i;
        path[t] = tag;
        if (t >= 1) tag = bpb[(size_t)t * NT + tag];
    }
}

// ---------------------------------------------------------------------------
extern "C" void kernel_launch(void* const* d_in, const int* in_sizes, int n_in,
                              void* d_out, int out_size, void* d_ws, size_t ws_size,
                              hipStream_t stream)
{
    const int* sent = (const int*)d_in[0];
    const int* csent = (const int*)d_in[1];
    const float* wemb = (const float*)d_in[2];
    const float* cemb = (const float*)d_in[3];
    const float* cWih_f = (const float*)d_in[4];
    const float* cWhh_f = (const float*)d_in[5];
    const float* cb_f = (const float*)d_in[6];
    const float* cWih_b = (const float*)d_in[7];
    const float* cWhh_b = (const float*)d_in[8];
    const float* cb_b = (const float*)d_in[9];
    const float* wWih_f = (const float*)d_in[10];
    const float* wWhh_f = (const float*)d_in[11];
    const float* wb_f = (const float*)d_in[12];
    const float* wWih_b = (const float*)d_in[13];
    const float* wWhh_b = (const float*)d_in[14];
    const float* wb_b = (const float*)d_in[15];
    const float* Wtag = (const float*)d_in[16];
    const float* btag = (const float*)d_in[17];
    const float* start_t = (const float*)d_in[18];
    const float* end_t = (const float*)d_in[19];
    const float* trans = (const float*)d_in[20];
    int* path = (int*)d_out;

    float* ws = (float*)d_ws;
    float* we_g = ws;                                   // SQ*EDIM
    float* cgx  = we_g + (size_t)SQ * EDIM;             // 2*SQ*512
    float* cho  = cgx + (size_t)2 * SQ * 512;           // SQ*256
    float* wgx  = cho + (size_t)SQ * 256;               // 2*SQ*2048
    float* lstm = wgx + (size_t)2 * SQ * 2048;          // SQ*1024
    float* emis = lstm + (size_t)SQ * 1024;             // SQ*NT
    ull* pairs  = (ull*)(emis + (size_t)SQ * NT);       // 5120 ulongs (40KB)
    int* map_   = (int*)(pairs + 5120);                 // 64*NT
    int* lastp  = map_ + 64 * NT;                       // 1 (+pad)
    unsigned char* bpb = (unsigned char*)(lastp + 4);   // SQ*NT bytes

    (void)hipMemsetAsync(pairs, 0, 5120 * sizeof(ull), stream);

    k1_gather_cgx<<<SQ / 16, 256, 0, stream>>>(sent, csent, wemb, cemb,
                                               cWih_f, cb_f, cWih_b, cb_b, we_g, cgx);
    k2_charlstm_gemm<<<2 + 2048, 1024, 0, stream>>>(cWhh_f, cWhh_b, cgx, cho, we_g,
                                                    wWih_f, wb_f, wWih_b, wb_b, wgx);
    k3_gemm_char<<<2048, 512, 0, stream>>>(cho, wWih_f, wWih_b, wgx);
    k4_word_lstm<<<256, 1024, 0, stream>>>(wWhh_f, wWhh_b, wgx, lstm, pairs);
    k5_emis<<<SQ, 64, 0, stream>>>(lstm, Wtag, btag, emis);
    k6a_viterbi<<<1, 256, 0, stream>>>(emis, start_t, end_t, trans, bpb, lastp);
    k6b_maps<<<64, 64, 0, stream>>>(bpb, map_);
    k6c_backtrack<<<1, 64, 0, stream>>>(bpb, map_, lastp, path);
}